// Round 4
// baseline (153.583 us; speedup 1.0000x reference)
//
#include <hip/hip_runtime.h>

// Normalized-Hermite per-dim prefactors: c_n = (2^n * n! * sqrt(pi))^{-1/2}
#define C0 0.7511255444649425f
#define C1 0.5311259660135985f
#define C2 0.2655629830067992f
#define C3 0.1084156342944575f

typedef float f4 __attribute__((ext_vector_type(4)));

// Persistent-block structure (fill-shaped): 1024 sites per block, 4 phases.
// Block cooperatively loads its whole x-slice (12 KB) via coalesced f4 loads
// into LDS once -> no strided global reads, no per-wave cold-load latency in
// the compute phases. Each phase: compute 256 sites from LDS, stage 16 KB
// swizzled in LDS, store as fully-coalesced nontemporal f4 stream.
__global__ __launch_bounds__(256) void hermite_orbitals_kernel(
    const float* __restrict__ x, float* __restrict__ out, int nsites)
{
    __shared__ float lds_x[3072];   // 12 KB: x for 1024 sites
    __shared__ f4 sh[1024];         // 16 KB staging (256 sites per phase)

    const int t = threadIdx.x;
    const int b = blockIdx.x;

    // ---- Cooperative coalesced x load: 768 f4 = 12 KB per block ----
    const f4* xv = reinterpret_cast<const f4*>(x);
    const long xf4_base = (long)b * 768;
    const long xf4_count = ((long)nsites * 3) >> 2;
#pragma unroll
    for (int k = 0; k < 3; ++k) {
        const long idx = xf4_base + t + (k << 8);
        if (idx < xf4_count)
            reinterpret_cast<f4*>(lds_x)[t + (k << 8)] =
                __builtin_nontemporal_load(&xv[idx]);
    }
    __syncthreads();

    f4* ob = reinterpret_cast<f4*>(out) + ((long)b << 12);  // 4096 f4/block
    const long of4_rem = ((long)nsites << 2) - ((long)b << 12);

#pragma unroll
    for (int p = 0; p < 4; ++p) {
        const int sl = (p << 8) + t;   // site within block
        const float x0 = lds_x[3 * sl + 0];
        const float x1 = lds_x[3 * sl + 1];
        const float x2 = lds_x[3 * sl + 2];

        const float t0 = x0 * x0, t1 = x1 * x1, t2 = x2 * x2;
        const float env = __expf(-0.5f * (t0 + t1 + t2));

        // Per-dim normalized Hermite: H0=1, H1=2x, H2=4x^2-2, H3=4x(2x^2-3)
        const float Y1 = (2.0f * C1) * x1;
        const float Y2 = C2 * (4.0f * t1 - 2.0f);
        const float Y3 = (4.0f * C3) * x1 * (2.0f * t1 - 3.0f);

        const float Z1 = (2.0f * C1) * x2;
        const float Z2 = C2 * (4.0f * t2 - 2.0f);
        const float Z3 = (4.0f * C3) * x2 * (2.0f * t2 - 3.0f);

        const float e0 = env * C0;
        const float e1 = env * (2.0f * C1) * x0;
        const float e2 = env * C2 * (4.0f * t0 - 2.0f);
        const float e3 = env * (4.0f * C3) * x0 * (2.0f * t0 - 3.0f);

        const float w00 = e0 * C0;
        const float w01 = e0 * Y1;
        const float w02 = e0 * Y2;
        const float w03 = e0 * Y3;
        const float w10 = e1 * C0;
        const float w11 = e1 * Y1;
        const float w20 = e2 * C0;

        // Orbital table (stable-sort-by-sum multi-index order, P=16):
        //  0:(0,0,0)  1:(0,0,1)  2:(0,1,0)  3:(1,0,0)
        //  4:(0,0,2)  5:(0,1,1)  6:(0,2,0)  7:(1,0,1)
        //  8:(1,1,0)  9:(2,0,0) 10:(0,0,3) 11:(0,1,2)
        // 12:(0,2,1) 13:(0,3,0) 14:(1,0,2) 15:(1,1,1)
        f4 r0, r1, r2v, r3;
        r0.x = w00 * C0;   // p0
        r0.y = w00 * Z1;   // p1
        r0.z = w01 * C0;   // p2
        r0.w = w10 * C0;   // p3

        r1.x = w00 * Z2;   // p4
        r1.y = w01 * Z1;   // p5
        r1.z = w02 * C0;   // p6
        r1.w = w10 * Z1;   // p7

        r2v.x = w11 * C0;  // p8
        r2v.y = w20 * C0;  // p9
        r2v.z = w00 * Z3;  // p10
        r2v.w = w01 * Z2;  // p11

        r3.x = w02 * Z1;   // p12
        r3.y = w03 * C0;   // p13
        r3.z = w10 * Z2;   // p14
        r3.w = w11 * Z1;   // p15

        // Swizzled staging write: quad k of site t at slot (k+t)&3
        sh[(t << 2) + (((0 + t) & 3))] = r0;
        sh[(t << 2) + (((1 + t) & 3))] = r1;
        sh[(t << 2) + (((2 + t) & 3))] = r2v;
        sh[(t << 2) + (((3 + t) & 3))] = r3;

        __syncthreads();

        // Coalesced nontemporal store: 1024 contiguous f4 per phase
#pragma unroll
        for (int k = 0; k < 4; ++k) {
            const int j = t + (k << 8);
            const int m = j >> 2;
            const int q = j & 3;
            const long oidx = (long)(p << 10) + j;
            if (oidx < of4_rem)
                __builtin_nontemporal_store(sh[(m << 2) + ((q + m) & 3)],
                                            &ob[oidx]);
        }
        if (p < 3) __syncthreads();
    }
}

extern "C" void kernel_launch(void* const* d_in, const int* in_sizes, int n_in,
                              void* d_out, int out_size, void* d_ws, size_t ws_size,
                              hipStream_t stream) {
    const float* x = (const float*)d_in[0];
    float* out = (float*)d_out;

    const int nsites = in_sizes[0] / 3;            // W * A = 2,097,152
    const int grid = (nsites + 1023) / 1024;       // 1024 sites per block
    hermite_orbitals_kernel<<<grid, 256, 0, stream>>>(x, out, nsites);
}